// Round 1
// baseline (364.368 us; speedup 1.0000x reference)
//
#include <hip/hip_runtime.h>
#include <math.h>

#define XS 512
#define YS 512
#define WDIM 256
#define NCELLS (XS * YS)          // 262144
#define K1_BLOCKS 2048
#define K1_THREADS 256            // 4 waves/block -> 8192 waves, 32 cells/wave

// Kernel 1: per-cell squared L2 distance + hierarchical argmin.
// One wave (64 lanes x float4) covers exactly one 256-float W row per step.
__global__ __launch_bounds__(K1_THREADS) void som_dist_kernel(
    const float* __restrict__ x,
    const float* __restrict__ W,
    unsigned long long* __restrict__ ws) {
  const int lane = threadIdx.x & 63;
  const int waveInBlock = threadIdx.x >> 6;
  const int gw = blockIdx.x * (K1_THREADS / 64) + waveInBlock;

  // x fragment for this lane (same for every cell)
  const float4 xv = ((const float4*)x)[lane];

  float bestD = 3.4e38f;
  int bestI = 0;

  const int base = gw * 32;  // 32 consecutive cells per wave
#pragma unroll 4
  for (int c = 0; c < 32; ++c) {
    const int cell = base + c;
    const float4 wv = *((const float4*)(W + (size_t)cell * WDIM) + lane);
    const float dx = xv.x - wv.x;
    const float dy = xv.y - wv.y;
    const float dz = xv.z - wv.z;
    const float dw = xv.w - wv.w;
    float s = dx * dx + dy * dy + dz * dz + dw * dw;
    // 64-lane butterfly sum; all lanes end with the total
#pragma unroll
    for (int off = 32; off > 0; off >>= 1) s += __shfl_xor(s, off, 64);
    // strict < keeps the earliest (lowest) index on ties, matching argmin
    if (s < bestD) { bestD = s; bestI = cell; }
  }

  // pack: fp32 dist (>=0) bit pattern is order-monotone as u32; index in low 32
  const unsigned long long packed =
      ((unsigned long long)__float_as_uint(bestD) << 32) | (unsigned int)bestI;

  __shared__ unsigned long long sbest[K1_THREADS / 64];
  if (lane == 0) sbest[waveInBlock] = packed;
  __syncthreads();
  if (threadIdx.x == 0) {
    unsigned long long m = sbest[0];
#pragma unroll
    for (int i = 1; i < K1_THREADS / 64; ++i) {
      const unsigned long long v = sbest[i];
      m = (v < m) ? v : m;
    }
    ws[blockIdx.x] = m;  // every slot written every call (ws is re-poisoned)
  }
}

// Kernel 2: every block redundantly reduces the 2048 per-block bests (L2-hot),
// then writes its slice of h; block 0 appends wx, wy.
__global__ __launch_bounds__(256) void som_h_kernel(
    const unsigned long long* __restrict__ ws,
    const int* __restrict__ time_step,
    float* __restrict__ out) {
  __shared__ unsigned long long red[256];
  const int t = threadIdx.x;

  unsigned long long m = 0xFFFFFFFFFFFFFFFFULL;
#pragma unroll
  for (int k = 0; k < K1_BLOCKS / 256; ++k) {
    const unsigned long long v = ws[t + 256 * k];
    m = (v < m) ? v : m;
  }
  red[t] = m;
  __syncthreads();
  for (int s = 128; s > 0; s >>= 1) {
    if (t < s) {
      const unsigned long long v = red[t + s];
      if (v < red[t]) red[t] = v;
    }
    __syncthreads();
  }
  const int flat = (int)(red[0] & 0xFFFFFFFFULL);
  const int wx = flat >> 9;       // flat / 512
  const int wy = flat & (YS - 1); // flat % 512

  // decay = SIGMA * exp(-t / (1000/ln(SIGMA))), SIGMA = 2
  const float ts = (float)(*time_step);
  const float TIME_CONST = 1442.6950408889634f;  // 1000 / ln(2)
  const float decay = 2.0f * expf(-ts / TIME_CONST);
  const float denom = 2.0f * decay * decay;
  const float inv = -1.0f / denom;

  // h[i][j] = exp(-((i-wx)^2 + (j-wy)^2) / denom); 4 elems (one float4)/thread
  const int e = blockIdx.x * 1024 + t * 4;
  const int i = e >> 9;
  const int j0 = e & (YS - 1);
  const float di = (float)(i - wx);
  const float di2 = di * di;

  float4 r;
  {
    const float d0 = (float)(j0 + 0 - wy);
    const float d1 = (float)(j0 + 1 - wy);
    const float d2 = (float)(j0 + 2 - wy);
    const float d3 = (float)(j0 + 3 - wy);
    r.x = expf((di2 + d0 * d0) * inv);
    r.y = expf((di2 + d1 * d1) * inv);
    r.z = expf((di2 + d2 * d2) * inv);
    r.w = expf((di2 + d3 * d3) * inv);
  }
  ((float4*)out)[e >> 2] = r;

  if (blockIdx.x == 0 && t == 0) {
    out[NCELLS] = (float)wx;      // output order: h, wx, wy
    out[NCELLS + 1] = (float)wy;
  }
}

extern "C" void kernel_launch(void* const* d_in, const int* in_sizes, int n_in,
                              void* d_out, int out_size, void* d_ws, size_t ws_size,
                              hipStream_t stream) {
  const float* x = (const float*)d_in[0];
  const float* W = (const float*)d_in[1];
  const int* ts = (const int*)d_in[2];
  float* out = (float*)d_out;
  unsigned long long* ws = (unsigned long long*)d_ws;

  som_dist_kernel<<<K1_BLOCKS, K1_THREADS, 0, stream>>>(x, W, ws);
  som_h_kernel<<<NCELLS / 1024, 256, 0, stream>>>(ws, ts, out);
}

// Round 3
// 346.837 us; speedup vs baseline: 1.0505x; 1.0505x over previous
//
#include <hip/hip_runtime.h>
#include <math.h>

#define XS 512
#define YS 512
#define WDIM 256
#define NCELLS (XS * YS)          // 262144
#define K1_BLOCKS 2048
#define K1_THREADS 256            // 4 waves/block, 32 cells/wave

typedef float vfloat4 __attribute__((ext_vector_type(4)));  // native vec for nontemporal builtin

// Kernel 1: per-cell squared L2 distance; hierarchical argmin ending in a
// single u64 atomicMin per block into ws[0].
// One wave (64 lanes x float4) covers exactly one 256-float W row per load.
__global__ __launch_bounds__(K1_THREADS) void som_dist_kernel(
    const float* __restrict__ x,
    const float* __restrict__ W,
    unsigned long long* __restrict__ ws) {
  const int lane = threadIdx.x & 63;
  const int waveInBlock = threadIdx.x >> 6;
  const int gw = blockIdx.x * (K1_THREADS / 64) + waveInBlock;

  const vfloat4 xv = ((const vfloat4*)x)[lane];

  float bestD = 3.4e38f;
  int bestI = 0;

  const int base = gw * 32;  // 32 consecutive cells per wave
#pragma unroll 8
  for (int c = 0; c < 32; ++c) {
    const int cell = base + c;
    const vfloat4* p = (const vfloat4*)(W + (size_t)cell * WDIM) + lane;
    const vfloat4 wv = __builtin_nontemporal_load(p);  // streaming: skip L2 retention
    const float dx = xv.x - wv.x;
    const float dy = xv.y - wv.y;
    const float dz = xv.z - wv.z;
    const float dw = xv.w - wv.w;
    float s = dx * dx + dy * dy + dz * dz + dw * dw;
#pragma unroll
    for (int off = 32; off > 0; off >>= 1) s += __shfl_xor(s, off, 64);
    // strict < keeps the lowest index on ties, matching argmin
    if (s < bestD) { bestD = s; bestI = cell; }
  }

  // fp32 dist (>=0) bit pattern is order-monotone as u32; index in low 32
  const unsigned long long packed =
      ((unsigned long long)__float_as_uint(bestD) << 32) | (unsigned int)bestI;

  __shared__ unsigned long long sbest[K1_THREADS / 64];
  if (lane == 0) sbest[waveInBlock] = packed;
  __syncthreads();
  if (threadIdx.x == 0) {
    unsigned long long m = sbest[0];
#pragma unroll
    for (int i = 1; i < K1_THREADS / 64; ++i) {
      const unsigned long long v = sbest[i];
      m = (v < m) ? v : m;
    }
    atomicMin(ws, m);  // device-scope; 2048 total, uncontended
  }
}

// Kernel 2: broadcast-read the winner, write h; block 0 appends wx, wy.
__global__ __launch_bounds__(256) void som_h_kernel(
    const unsigned long long* __restrict__ ws,
    const int* __restrict__ time_step,
    float* __restrict__ out) {
  const int t = threadIdx.x;
  const unsigned long long packed = *ws;   // wave-uniform; L2-hot broadcast
  const int flat = (int)(packed & 0xFFFFFFFFULL);
  const int wx = flat >> 9;       // flat / 512
  const int wy = flat & (YS - 1); // flat % 512

  // decay = SIGMA * exp(-t / (1000/ln(SIGMA))), SIGMA = 2
  const float ts = (float)(*time_step);
  const float TIME_CONST = 1442.6950408889634f;  // 1000 / ln(2)
  const float decay = 2.0f * expf(-ts / TIME_CONST);
  const float denom = 2.0f * decay * decay;
  const float inv = -1.0f / denom;

  // h[i][j] = exp(-((i-wx)^2 + (j-wy)^2) / denom); one float4 per thread
  const int e = blockIdx.x * 1024 + t * 4;
  const int i = e >> 9;
  const int j0 = e & (YS - 1);
  const float di = (float)(i - wx);
  const float di2 = di * di;

  const float d0 = (float)(j0 + 0 - wy);
  const float d1 = (float)(j0 + 1 - wy);
  const float d2 = (float)(j0 + 2 - wy);
  const float d3 = (float)(j0 + 3 - wy);
  vfloat4 r;
  r.x = expf((di2 + d0 * d0) * inv);
  r.y = expf((di2 + d1 * d1) * inv);
  r.z = expf((di2 + d2 * d2) * inv);
  r.w = expf((di2 + d3 * d3) * inv);
  ((vfloat4*)out)[e >> 2] = r;

  if (blockIdx.x == 0 && t == 0) {
    out[NCELLS] = (float)wx;      // output order: h, wx, wy
    out[NCELLS + 1] = (float)wy;
  }
}

extern "C" void kernel_launch(void* const* d_in, const int* in_sizes, int n_in,
                              void* d_out, int out_size, void* d_ws, size_t ws_size,
                              hipStream_t stream) {
  const float* x = (const float*)d_in[0];
  const float* W = (const float*)d_in[1];
  const int* ts = (const int*)d_in[2];
  float* out = (float*)d_out;
  unsigned long long* ws = (unsigned long long*)d_ws;

  // ws[0] := 0xFFFFFFFFFFFFFFFF so atomicMin never depends on poison value.
  (void)hipMemsetAsync(ws, 0xFF, 8, stream);
  som_dist_kernel<<<K1_BLOCKS, K1_THREADS, 0, stream>>>(x, W, ws);
  som_h_kernel<<<NCELLS / 1024, 256, 0, stream>>>(ws, ts, out);
}